// Round 1
// baseline (9192.542 us; speedup 1.0000x reference)
//
#include <hip/hip_runtime.h>

#define BT 1024   // batch
#define TT 512    // total timesteps

__device__ __forceinline__ float sig_(float x) { return 1.f / (1.f + __expf(-x)); }
__device__ __forceinline__ float th_(float x)  { return 1.f - 2.f / (1.f + __expf(2.f * x)); }

// ---------------------------------------------------------------------------
// pre[R][n] = sum_k Arow(R)[k] * W[n][k] + bih[n] + bhh[n]
// Row R = tl*1024 + b  (t-major within chunk, batch inner) so the recurrent
// kernel reads contiguous [b][n] slices per timestep.
// XMODE=true : A = x [B][T][K], row src = x + (b*TT + t0+tl)*K
// XMODE=false: A = h1seq, contiguous rows of length K.
// ---------------------------------------------------------------------------
template <int K, int KPAD, int N, bool XMODE>
__global__ __launch_bounds__(256) void gemm_pre(
    const float* __restrict__ A, const float* __restrict__ W,
    const float* __restrict__ bih, const float* __restrict__ bhh,
    float* __restrict__ out, int t0)
{
    __shared__ float As[128][KPAD];              // KPAD = K+1: 8-row lane stride -> <=2-way banks
    __shared__ __align__(16) float Bs[K][64];
    const int tid = threadIdx.x;
    const int n0 = blockIdx.x * 64;
    const int Rbase = blockIdx.y * 128;
    const int NQ = K / 4;

    // A tile: 128 rows x K, float4 per row-chunk, coalesced within rows
    for (int ii = tid; ii < 128 * NQ; ii += 256) {
        int r = ii / NQ, q = ii % NQ;
        const float* src;
        if (XMODE) {
            int b  = (blockIdx.y & 7) * 128 + r;   // 1024/128 = 8 blocks per tl
            int tl = blockIdx.y >> 3;
            src = A + ((size_t)b * TT + (t0 + tl)) * K;
        } else {
            src = A + (size_t)(Rbase + r) * K;
        }
        float4 v = *(const float4*)(src + q * 4);
        As[r][q * 4 + 0] = v.x; As[r][q * 4 + 1] = v.y;
        As[r][q * 4 + 2] = v.z; As[r][q * 4 + 3] = v.w;
    }
    // B tile transposed: Bs[k][n] = W[n0+n][k]; lane-gather from L2-hot W
    for (int ii = tid; ii < 64 * NQ; ii += 256) {
        int n = ii & 63, kq = ii >> 6;
        float4 v = make_float4(0.f, 0.f, 0.f, 0.f);
        if (n0 + n < N) v = *(const float4*)(W + (size_t)(n0 + n) * K + kq * 4);
        Bs[kq * 4 + 0][n] = v.x; Bs[kq * 4 + 1][n] = v.y;
        Bs[kq * 4 + 2][n] = v.z; Bs[kq * 4 + 3][n] = v.w;
    }
    __syncthreads();

    const int tx = tid & 15, ty = tid >> 4;      // 16x16 threads, 8x4 micro-tile
    float acc[8][4];
#pragma unroll
    for (int i = 0; i < 8; i++)
#pragma unroll
        for (int jj = 0; jj < 4; jj++) acc[i][jj] = 0.f;

#pragma unroll 4
    for (int k = 0; k < K; k++) {
        float4 bv = *(const float4*)&Bs[k][tx * 4];
#pragma unroll
        for (int i = 0; i < 8; i++) {
            float a = As[ty * 8 + i][k];
            acc[i][0] += a * bv.x; acc[i][1] += a * bv.y;
            acc[i][2] += a * bv.z; acc[i][3] += a * bv.w;
        }
    }
    int n = n0 + tx * 4;
    if (n < N) {
        float4 bias;
        bias.x = bih[n] + bhh[n];     bias.y = bih[n + 1] + bhh[n + 1];
        bias.z = bih[n + 2] + bhh[n + 2]; bias.w = bih[n + 3] + bhh[n + 3];
#pragma unroll
        for (int i = 0; i < 8; i++) {
            size_t R = (size_t)Rbase + ty * 8 + i;
            float4 o;
            o.x = acc[i][0] + bias.x; o.y = acc[i][1] + bias.y;
            o.z = acc[i][2] + bias.z; o.w = acc[i][3] + bias.w;
            *(float4*)(out + R * N + n) = o;
        }
    }
}

// ---------------------------------------------------------------------------
// rec1: layer-1 recurrence. 256 WGs x 832 thr, 4 batch elems per WG.
// unit (j in [0,100), gate in [0,4), khalf in [0,2)) -> 800 active threads.
// Whh row-half (52 floats, zero-padded past k=100) stays in VGPRs all launch;
// h lives in LDS (pad cols 100..103 = 0); pre slices double-buffered in LDS
// with register prefetch of t+1 issued before the k-loop.
// ---------------------------------------------------------------------------
__global__ __launch_bounds__(832) void rec1(
    const float* __restrict__ pre,   // [Tc][1024][400]
    const float* __restrict__ Whh,   // [400][100]
    float* __restrict__ hseq,        // [Tc][1024][100]
    float* __restrict__ cst,         // [1024][100]
    int Tc, int first)
{
    __shared__ __align__(16) float hs[4][104];
    __shared__ float pres[2][1600];
    __shared__ float gbuf[1600];
    const int tid = threadIdx.x;
    const int b0 = blockIdx.x * 4;
    const bool act = tid < 800;
    const int j  = tid >> 3;
    const int g  = (tid >> 1) & 3;
    const int kh = tid & 1;

    float w[52];
    if (act) {
        const int row = g * 100 + j;
#pragma unroll
        for (int kk = 0; kk < 52; kk++) {
            int k = kh * 52 + kk;
            w[kk] = (k < 100) ? Whh[row * 100 + k] : 0.f;
        }
    }
    const bool upd = tid < 400;
    const int ub = tid / 100, uj = tid % 100;
    float c = 0.f;
    if (upd) {
        if (first) {
            hs[ub][uj] = 0.f;
        } else {
            hs[ub][uj] = hseq[((size_t)(Tc - 1) * BT + b0 + ub) * 100 + uj];  // prev chunk's last h
            c = cst[(size_t)(b0 + ub) * 100 + uj];
        }
    }
    if (tid < 16) hs[tid >> 2][100 + (tid & 3)] = 0.f;  // zero pads
    for (int i = tid; i < 1600; i += 832)
        pres[0][i] = pre[(size_t)(b0 + i / 400) * 400 + (i % 400)];   // stage t=0
    const size_t pfA = (size_t)(b0 + tid / 400) * 400 + (tid % 400);
    const size_t pfB = (size_t)(b0 + (tid + 800) / 400) * 400 + ((tid + 800) % 400);
    __syncthreads();

    int cur = 0;
    for (int t = 0; t < Tc; t++) {
        // prefetch t+1 pre slice into registers (hidden under the k-loop)
        int tn = (t + 1 < Tc) ? (t + 1) : t;
        const float* pn = pre + (size_t)tn * BT * 400;
        float pf0 = pn[pfA];
        float pf1 = (tid < 800) ? pn[pfB] : 0.f;

        float a0 = 0.f, a1 = 0.f, a2 = 0.f, a3 = 0.f;
        if (act) {
            const float4* h0 = (const float4*)&hs[0][kh * 52];
            const float4* h1 = (const float4*)&hs[1][kh * 52];
            const float4* h2 = (const float4*)&hs[2][kh * 52];
            const float4* h3 = (const float4*)&hs[3][kh * 52];
#pragma unroll
            for (int q = 0; q < 13; q++) {
                float4 v0 = h0[q], v1 = h1[q], v2 = h2[q], v3 = h3[q];
                a0 += w[q*4+0]*v0.x + w[q*4+1]*v0.y + w[q*4+2]*v0.z + w[q*4+3]*v0.w;
                a1 += w[q*4+0]*v1.x + w[q*4+1]*v1.y + w[q*4+2]*v1.z + w[q*4+3]*v1.w;
                a2 += w[q*4+0]*v2.x + w[q*4+1]*v2.y + w[q*4+2]*v2.z + w[q*4+3]*v2.w;
                a3 += w[q*4+0]*v3.x + w[q*4+1]*v3.y + w[q*4+2]*v3.z + w[q*4+3]*v3.w;
            }
        }
        a0 += __shfl_xor(a0, 1); a1 += __shfl_xor(a1, 1);
        a2 += __shfl_xor(a2, 1); a3 += __shfl_xor(a3, 1);
        if (act && kh == 0) {
            int idx = g * 100 + j;
            gbuf[idx] = a0; gbuf[400 + idx] = a1; gbuf[800 + idx] = a2; gbuf[1200 + idx] = a3;
        }
        __syncthreads();
        if (upd) {
            const float* gb = gbuf + ub * 400;
            const float* pb = pres[cur] + ub * 400;
            float xi = gb[uj]       + pb[uj];
            float xf = gb[100 + uj] + pb[100 + uj];
            float xg = gb[200 + uj] + pb[200 + uj];
            float xo = gb[300 + uj] + pb[300 + uj];
            float ii = sig_(xi), ff = sig_(xf), gg = th_(xg), oo = sig_(xo);
            c = ff * c + ii * gg;
            float h = oo * th_(c);
            hs[ub][uj] = h;
            hseq[((size_t)t * BT + b0 + ub) * 100 + uj] = h;   // coalesced 400B segments
        }
        pres[cur ^ 1][tid] = pf0;
        if (tid < 800) pres[cur ^ 1][tid + 800] = pf1;
        __syncthreads();
        cur ^= 1;
    }
    if (upd) cst[(size_t)(b0 + ub) * 100 + uj] = c;
}

// ---------------------------------------------------------------------------
// rec2: layer-2 recurrence (H=50). Same structure at half size; no hidden
// sequence output — only state carry and the final [1024,50] -> d_out.
// ---------------------------------------------------------------------------
__global__ __launch_bounds__(448) void rec2(
    const float* __restrict__ pre2,  // [Tc][1024][200]
    const float* __restrict__ Whh,   // [200][50]
    float* __restrict__ cst, float* __restrict__ hst,  // [1024][50]
    float* __restrict__ out,         // [1024][50]
    int Tc, int first)
{
    __shared__ __align__(16) float hs[4][56];
    __shared__ float pres[2][800];
    __shared__ float gbuf[800];
    const int tid = threadIdx.x;
    const int b0 = blockIdx.x * 4;
    const bool act = tid < 400;
    const int j  = tid >> 3;
    const int g  = (tid >> 1) & 3;
    const int kh = tid & 1;

    float w[28];
    if (act) {
        const int row = g * 50 + j;
#pragma unroll
        for (int kk = 0; kk < 28; kk++) {
            int k = kh * 28 + kk;
            w[kk] = (k < 50) ? Whh[row * 50 + k] : 0.f;
        }
    }
    const bool upd = tid < 200;
    const int ub = tid / 50, uj = tid % 50;
    float c = 0.f, h = 0.f;
    if (upd) {
        if (!first) {
            h = hst[(size_t)(b0 + ub) * 50 + uj];
            c = cst[(size_t)(b0 + ub) * 50 + uj];
        }
        hs[ub][uj] = h;
    }
    if (tid < 24) hs[tid / 6][50 + tid % 6] = 0.f;
    for (int i = tid; i < 800; i += 448)
        pres[0][i] = pre2[(size_t)(b0 + i / 200) * 200 + (i % 200)];
    const size_t pfA = (size_t)(b0 + tid / 200) * 200 + (tid % 200);
    const size_t pfB = (size_t)(b0 + (tid + 448) / 200) * 200 + ((tid + 448) % 200);
    __syncthreads();

    int cur = 0;
    for (int t = 0; t < Tc; t++) {
        int tn = (t + 1 < Tc) ? (t + 1) : t;
        const float* pn = pre2 + (size_t)tn * BT * 200;
        float pf0 = pn[pfA];
        float pf1 = (tid < 352) ? pn[pfB] : 0.f;

        float a0 = 0.f, a1 = 0.f, a2 = 0.f, a3 = 0.f;
        if (act) {
            const float4* h0 = (const float4*)&hs[0][kh * 28];
            const float4* h1 = (const float4*)&hs[1][kh * 28];
            const float4* h2 = (const float4*)&hs[2][kh * 28];
            const float4* h3 = (const float4*)&hs[3][kh * 28];
#pragma unroll
            for (int q = 0; q < 7; q++) {
                float4 v0 = h0[q], v1 = h1[q], v2 = h2[q], v3 = h3[q];
                a0 += w[q*4+0]*v0.x + w[q*4+1]*v0.y + w[q*4+2]*v0.z + w[q*4+3]*v0.w;
                a1 += w[q*4+0]*v1.x + w[q*4+1]*v1.y + w[q*4+2]*v1.z + w[q*4+3]*v1.w;
                a2 += w[q*4+0]*v2.x + w[q*4+1]*v2.y + w[q*4+2]*v2.z + w[q*4+3]*v2.w;
                a3 += w[q*4+0]*v3.x + w[q*4+1]*v3.y + w[q*4+2]*v3.z + w[q*4+3]*v3.w;
            }
        }
        a0 += __shfl_xor(a0, 1); a1 += __shfl_xor(a1, 1);
        a2 += __shfl_xor(a2, 1); a3 += __shfl_xor(a3, 1);
        if (act && kh == 0) {
            int idx = g * 50 + j;
            gbuf[idx] = a0; gbuf[200 + idx] = a1; gbuf[400 + idx] = a2; gbuf[600 + idx] = a3;
        }
        __syncthreads();
        if (upd) {
            const float* gb = gbuf + ub * 200;
            const float* pb = pres[cur] + ub * 200;
            float xi = gb[uj]       + pb[uj];
            float xf = gb[50 + uj]  + pb[50 + uj];
            float xg = gb[100 + uj] + pb[100 + uj];
            float xo = gb[150 + uj] + pb[150 + uj];
            float ii = sig_(xi), ff = sig_(xf), gg = th_(xg), oo = sig_(xo);
            c = ff * c + ii * gg;
            h = oo * th_(c);
            hs[ub][uj] = h;
        }
        pres[cur ^ 1][tid] = pf0;
        if (tid < 352) pres[cur ^ 1][tid + 448] = pf1;
        __syncthreads();
        cur ^= 1;
    }
    if (upd) {
        cst[(size_t)(b0 + ub) * 50 + uj] = c;
        hst[(size_t)(b0 + ub) * 50 + uj] = h;
        out[(size_t)(b0 + ub) * 50 + uj] = h;
    }
}

// ---------------------------------------------------------------------------
extern "C" void kernel_launch(void* const* d_in, const int* in_sizes, int n_in,
                              void* d_out, int out_size, void* d_ws, size_t ws_size,
                              hipStream_t stream)
{
    const float* x    = (const float*)d_in[0];
    const float* Wih1 = (const float*)d_in[1];
    const float* Whh1 = (const float*)d_in[2];
    const float* bih1 = (const float*)d_in[3];
    const float* bhh1 = (const float*)d_in[4];
    const float* Wih2 = (const float*)d_in[5];
    const float* Whh2 = (const float*)d_in[6];
    const float* bih2 = (const float*)d_in[7];
    const float* bhh2 = (const float*)d_in[8];
    float* out = (float*)d_out;
    float* ws  = (float*)d_ws;

    // Chunk T so scratch fits: per chunk pre1 [Tc,1024,400] + h1seq [Tc,1024,100]
    // + pre2 [Tc,1024,200] + small states. Tc=64 -> ~185 MB.
    int Tc = 64;
    auto need = [](int tc) -> size_t {
        return ((size_t)tc * 1024 * (400 + 100 + 200) +
                (size_t)1024 * 100 + (size_t)1024 * 50 * 2) * sizeof(float);
    };
    while (Tc > 1 && need(Tc) > ws_size) Tc >>= 1;

    float* pre1 = ws;
    float* h1s  = pre1 + (size_t)Tc * 1024 * 400;
    float* pre2 = h1s  + (size_t)Tc * 1024 * 100;
    float* c1   = pre2 + (size_t)Tc * 1024 * 200;
    float* c2   = c1 + 1024 * 100;
    float* h2st = c2 + 1024 * 50;

    const int nch = TT / Tc;
    for (int ch = 0; ch < nch; ch++) {
        int t0 = ch * Tc;
        gemm_pre<80, 81, 400, true ><<<dim3(7, Tc * 8), 256, 0, stream>>>(
            x, Wih1, bih1, bhh1, pre1, t0);
        rec1<<<dim3(256), dim3(832), 0, stream>>>(pre1, Whh1, h1s, c1, Tc, ch == 0 ? 1 : 0);
        gemm_pre<100, 101, 200, false><<<dim3(4, Tc * 8), 256, 0, stream>>>(
            h1s, Wih2, bih2, bhh2, pre2, 0);
        rec2<<<dim3(256), dim3(448), 0, stream>>>(pre2, Whh2, c2, h2st, out, Tc, ch == 0 ? 1 : 0);
    }
}

// Round 2
// 9179.028 us; speedup vs baseline: 1.0015x; 1.0015x over previous
//
#include <hip/hip_runtime.h>

#define BT 1024   // batch
#define TT 512    // total timesteps

__device__ __forceinline__ float sig_(float x) { return 1.f / (1.f + __expf(-x)); }
__device__ __forceinline__ float th_(float x)  { return 1.f - 2.f / (1.f + __expf(2.f * x)); }

// ---------------------------------------------------------------------------
// pre[R][n] = sum_k Arow(R)[k] * W[n][k] + bih[n] + bhh[n]
// Row R = tl*1024 + b  (t-major within chunk, batch inner) so the recurrent
// kernel reads contiguous [b][n] slices per timestep.
// XMODE=true : A = x [B][T][K], row src = x + (b*TT + t0+tl)*K
// XMODE=false: A = h1seq, contiguous rows of length K.
// ---------------------------------------------------------------------------
template <int K, int KPAD, int N, bool XMODE>
__global__ __launch_bounds__(256) void gemm_pre(
    const float* __restrict__ A, const float* __restrict__ W,
    const float* __restrict__ bih, const float* __restrict__ bhh,
    float* __restrict__ out, int t0)
{
    __shared__ float As[128][KPAD];              // KPAD = K+1: 8-row lane stride -> <=2-way banks
    __shared__ __align__(16) float Bs[K][64];
    const int tid = threadIdx.x;
    const int n0 = blockIdx.x * 64;
    const int Rbase = blockIdx.y * 128;
    const int NQ = K / 4;

    // A tile: 128 rows x K, float4 per row-chunk, coalesced within rows
    for (int ii = tid; ii < 128 * NQ; ii += 256) {
        int r = ii / NQ, q = ii % NQ;
        const float* src;
        if (XMODE) {
            int b  = (blockIdx.y & 7) * 128 + r;   // 1024/128 = 8 blocks per tl
            int tl = blockIdx.y >> 3;
            src = A + ((size_t)b * TT + (t0 + tl)) * K;
        } else {
            src = A + (size_t)(Rbase + r) * K;
        }
        float4 v = *(const float4*)(src + q * 4);
        As[r][q * 4 + 0] = v.x; As[r][q * 4 + 1] = v.y;
        As[r][q * 4 + 2] = v.z; As[r][q * 4 + 3] = v.w;
    }
    // B tile transposed: Bs[k][n] = W[n0+n][k]; lane-gather from L2-hot W
    for (int ii = tid; ii < 64 * NQ; ii += 256) {
        int n = ii & 63, kq = ii >> 6;
        float4 v = make_float4(0.f, 0.f, 0.f, 0.f);
        if (n0 + n < N) v = *(const float4*)(W + (size_t)(n0 + n) * K + kq * 4);
        Bs[kq * 4 + 0][n] = v.x; Bs[kq * 4 + 1][n] = v.y;
        Bs[kq * 4 + 2][n] = v.z; Bs[kq * 4 + 3][n] = v.w;
    }
    __syncthreads();

    const int tx = tid & 15, ty = tid >> 4;      // 16x16 threads, 8x4 micro-tile
    float acc[8][4];
#pragma unroll
    for (int i = 0; i < 8; i++)
#pragma unroll
        for (int jj = 0; jj < 4; jj++) acc[i][jj] = 0.f;

#pragma unroll 4
    for (int k = 0; k < K; k++) {
        float4 bv = *(const float4*)&Bs[k][tx * 4];
#pragma unroll
        for (int i = 0; i < 8; i++) {
            float a = As[ty * 8 + i][k];
            acc[i][0] += a * bv.x; acc[i][1] += a * bv.y;
            acc[i][2] += a * bv.z; acc[i][3] += a * bv.w;
        }
    }
    int n = n0 + tx * 4;
    if (n < N) {
        float4 bias;
        bias.x = bih[n] + bhh[n];     bias.y = bih[n + 1] + bhh[n + 1];
        bias.z = bih[n + 2] + bhh[n + 2]; bias.w = bih[n + 3] + bhh[n + 3];
#pragma unroll
        for (int i = 0; i < 8; i++) {
            size_t R = (size_t)Rbase + ty * 8 + i;
            float4 o;
            o.x = acc[i][0] + bias.x; o.y = acc[i][1] + bias.y;
            o.z = acc[i][2] + bias.z; o.w = acc[i][3] + bias.w;
            *(float4*)(out + R * N + n) = o;
        }
    }
}

// ---------------------------------------------------------------------------
// rec1: layer-1 recurrence. 256 WGs x 832 thr, 4 batch elems per WG.
// unit (j in [0,100), gate in [0,4), khalf in [0,2)) -> 800 active threads.
// Whh row-half (52 floats, zero-padded past k=100) stays in VGPRs all launch;
// h lives in LDS (pad cols 100..103 = 0); pre slices double-buffered in LDS
// with register prefetch of t+1 issued before the k-loop.
//
// __launch_bounds__(832, 4): 4 waves/EU -> 128-VGPR budget. Round-1 default
// gave 64 VGPRs -> w[52] spilled to scratch -> 2.7 GB/dispatch HBM fetch
// (rocprof FETCH_SIZE matched 800thr*52*4B*256WG*64t exactly). Do not drop
// this attribute.
// ---------------------------------------------------------------------------
__global__ __launch_bounds__(832, 4) void rec1(
    const float* __restrict__ pre,   // [Tc][1024][400]
    const float* __restrict__ Whh,   // [400][100]
    float* __restrict__ hseq,        // [Tc][1024][100]
    float* __restrict__ cst,         // [1024][100]
    int Tc, int first)
{
    __shared__ __align__(16) float hs[4][104];
    __shared__ float pres[2][1600];
    __shared__ float gbuf[1600];
    const int tid = threadIdx.x;
    const int b0 = blockIdx.x * 4;
    const bool act = tid < 800;
    const int j  = tid >> 3;
    const int g  = (tid >> 1) & 3;
    const int kh = tid & 1;

    float w[52];
    if (act) {
        const int row = g * 100 + j;
#pragma unroll
        for (int kk = 0; kk < 52; kk++) {
            int k = kh * 52 + kk;
            w[kk] = (k < 100) ? Whh[row * 100 + k] : 0.f;
        }
    }
    const bool upd = tid < 400;
    const int ub = tid / 100, uj = tid % 100;
    float c = 0.f;
    if (upd) {
        if (first) {
            hs[ub][uj] = 0.f;
        } else {
            hs[ub][uj] = hseq[((size_t)(Tc - 1) * BT + b0 + ub) * 100 + uj];  // prev chunk's last h
            c = cst[(size_t)(b0 + ub) * 100 + uj];
        }
    }
    if (tid < 16) hs[tid >> 2][100 + (tid & 3)] = 0.f;  // zero pads
    for (int i = tid; i < 1600; i += 832)
        pres[0][i] = pre[(size_t)(b0 + i / 400) * 400 + (i % 400)];   // stage t=0
    const size_t pfA = (size_t)(b0 + tid / 400) * 400 + (tid % 400);
    const size_t pfB = (size_t)(b0 + (tid + 800) / 400) * 400 + ((tid + 800) % 400);
    __syncthreads();

    int cur = 0;
    for (int t = 0; t < Tc; t++) {
        // prefetch t+1 pre slice into registers (hidden under the k-loop)
        int tn = (t + 1 < Tc) ? (t + 1) : t;
        const float* pn = pre + (size_t)tn * BT * 400;
        float pf0 = pn[pfA];
        float pf1 = (tid < 800) ? pn[pfB] : 0.f;

        float a0 = 0.f, a1 = 0.f, a2 = 0.f, a3 = 0.f;
        if (act) {
            const float4* h0 = (const float4*)&hs[0][kh * 52];
            const float4* h1 = (const float4*)&hs[1][kh * 52];
            const float4* h2 = (const float4*)&hs[2][kh * 52];
            const float4* h3 = (const float4*)&hs[3][kh * 52];
#pragma unroll
            for (int q = 0; q < 13; q++) {
                float4 v0 = h0[q], v1 = h1[q], v2 = h2[q], v3 = h3[q];
                a0 += w[q*4+0]*v0.x + w[q*4+1]*v0.y + w[q*4+2]*v0.z + w[q*4+3]*v0.w;
                a1 += w[q*4+0]*v1.x + w[q*4+1]*v1.y + w[q*4+2]*v1.z + w[q*4+3]*v1.w;
                a2 += w[q*4+0]*v2.x + w[q*4+1]*v2.y + w[q*4+2]*v2.z + w[q*4+3]*v2.w;
                a3 += w[q*4+0]*v3.x + w[q*4+1]*v3.y + w[q*4+2]*v3.z + w[q*4+3]*v3.w;
            }
        }
        a0 += __shfl_xor(a0, 1); a1 += __shfl_xor(a1, 1);
        a2 += __shfl_xor(a2, 1); a3 += __shfl_xor(a3, 1);
        if (act && kh == 0) {
            int idx = g * 100 + j;
            gbuf[idx] = a0; gbuf[400 + idx] = a1; gbuf[800 + idx] = a2; gbuf[1200 + idx] = a3;
        }
        __syncthreads();
        if (upd) {
            const float* gb = gbuf + ub * 400;
            const float* pb = pres[cur] + ub * 400;
            float xi = gb[uj]       + pb[uj];
            float xf = gb[100 + uj] + pb[100 + uj];
            float xg = gb[200 + uj] + pb[200 + uj];
            float xo = gb[300 + uj] + pb[300 + uj];
            float ii = sig_(xi), ff = sig_(xf), gg = th_(xg), oo = sig_(xo);
            c = ff * c + ii * gg;
            float h = oo * th_(c);
            hs[ub][uj] = h;
            hseq[((size_t)t * BT + b0 + ub) * 100 + uj] = h;   // coalesced 400B segments
        }
        pres[cur ^ 1][tid] = pf0;
        if (tid < 800) pres[cur ^ 1][tid + 800] = pf1;
        __syncthreads();
        cur ^= 1;
    }
    if (upd) cst[(size_t)(b0 + ub) * 100 + uj] = c;
}

// ---------------------------------------------------------------------------
// rec2: layer-2 recurrence (H=50). Same structure at half size; no hidden
// sequence output — only state carry and the final [1024,50] -> d_out.
// __launch_bounds__(448, 4): same 128-VGPR budget rationale as rec1.
// ---------------------------------------------------------------------------
__global__ __launch_bounds__(448, 4) void rec2(
    const float* __restrict__ pre2,  // [Tc][1024][200]
    const float* __restrict__ Whh,   // [200][50]
    float* __restrict__ cst, float* __restrict__ hst,  // [1024][50]
    float* __restrict__ out,         // [1024][50]
    int Tc, int first)
{
    __shared__ __align__(16) float hs[4][56];
    __shared__ float pres[2][800];
    __shared__ float gbuf[800];
    const int tid = threadIdx.x;
    const int b0 = blockIdx.x * 4;
    const bool act = tid < 400;
    const int j  = tid >> 3;
    const int g  = (tid >> 1) & 3;
    const int kh = tid & 1;

    float w[28];
    if (act) {
        const int row = g * 50 + j;
#pragma unroll
        for (int kk = 0; kk < 28; kk++) {
            int k = kh * 28 + kk;
            w[kk] = (k < 50) ? Whh[row * 50 + k] : 0.f;
        }
    }
    const bool upd = tid < 200;
    const int ub = tid / 50, uj = tid % 50;
    float c = 0.f, h = 0.f;
    if (upd) {
        if (!first) {
            h = hst[(size_t)(b0 + ub) * 50 + uj];
            c = cst[(size_t)(b0 + ub) * 50 + uj];
        }
        hs[ub][uj] = h;
    }
    if (tid < 24) hs[tid / 6][50 + tid % 6] = 0.f;
    for (int i = tid; i < 800; i += 448)
        pres[0][i] = pre2[(size_t)(b0 + i / 200) * 200 + (i % 200)];
    const size_t pfA = (size_t)(b0 + tid / 200) * 200 + (tid % 200);
    const size_t pfB = (size_t)(b0 + (tid + 448) / 200) * 200 + ((tid + 448) % 200);
    __syncthreads();

    int cur = 0;
    for (int t = 0; t < Tc; t++) {
        int tn = (t + 1 < Tc) ? (t + 1) : t;
        const float* pn = pre2 + (size_t)tn * BT * 200;
        float pf0 = pn[pfA];
        float pf1 = (tid < 352) ? pn[pfB] : 0.f;

        float a0 = 0.f, a1 = 0.f, a2 = 0.f, a3 = 0.f;
        if (act) {
            const float4* h0 = (const float4*)&hs[0][kh * 28];
            const float4* h1 = (const float4*)&hs[1][kh * 28];
            const float4* h2 = (const float4*)&hs[2][kh * 28];
            const float4* h3 = (const float4*)&hs[3][kh * 28];
#pragma unroll
            for (int q = 0; q < 7; q++) {
                float4 v0 = h0[q], v1 = h1[q], v2 = h2[q], v3 = h3[q];
                a0 += w[q*4+0]*v0.x + w[q*4+1]*v0.y + w[q*4+2]*v0.z + w[q*4+3]*v0.w;
                a1 += w[q*4+0]*v1.x + w[q*4+1]*v1.y + w[q*4+2]*v1.z + w[q*4+3]*v1.w;
                a2 += w[q*4+0]*v2.x + w[q*4+1]*v2.y + w[q*4+2]*v2.z + w[q*4+3]*v2.w;
                a3 += w[q*4+0]*v3.x + w[q*4+1]*v3.y + w[q*4+2]*v3.z + w[q*4+3]*v3.w;
            }
        }
        a0 += __shfl_xor(a0, 1); a1 += __shfl_xor(a1, 1);
        a2 += __shfl_xor(a2, 1); a3 += __shfl_xor(a3, 1);
        if (act && kh == 0) {
            int idx = g * 50 + j;
            gbuf[idx] = a0; gbuf[200 + idx] = a1; gbuf[400 + idx] = a2; gbuf[600 + idx] = a3;
        }
        __syncthreads();
        if (upd) {
            const float* gb = gbuf + ub * 200;
            const float* pb = pres[cur] + ub * 200;
            float xi = gb[uj]       + pb[uj];
            float xf = gb[50 + uj]  + pb[50 + uj];
            float xg = gb[100 + uj] + pb[100 + uj];
            float xo = gb[150 + uj] + pb[150 + uj];
            float ii = sig_(xi), ff = sig_(xf), gg = th_(xg), oo = sig_(xo);
            c = ff * c + ii * gg;
            h = oo * th_(c);
            hs[ub][uj] = h;
        }
        pres[cur ^ 1][tid] = pf0;
        if (tid < 352) pres[cur ^ 1][tid + 448] = pf1;
        __syncthreads();
        cur ^= 1;
    }
    if (upd) {
        cst[(size_t)(b0 + ub) * 50 + uj] = c;
        hst[(size_t)(b0 + ub) * 50 + uj] = h;
        out[(size_t)(b0 + ub) * 50 + uj] = h;
    }
}

// ---------------------------------------------------------------------------
extern "C" void kernel_launch(void* const* d_in, const int* in_sizes, int n_in,
                              void* d_out, int out_size, void* d_ws, size_t ws_size,
                              hipStream_t stream)
{
    const float* x    = (const float*)d_in[0];
    const float* Wih1 = (const float*)d_in[1];
    const float* Whh1 = (const float*)d_in[2];
    const float* bih1 = (const float*)d_in[3];
    const float* bhh1 = (const float*)d_in[4];
    const float* Wih2 = (const float*)d_in[5];
    const float* Whh2 = (const float*)d_in[6];
    const float* bih2 = (const float*)d_in[7];
    const float* bhh2 = (const float*)d_in[8];
    float* out = (float*)d_out;
    float* ws  = (float*)d_ws;

    // Chunk T so scratch fits: per chunk pre1 [Tc,1024,400] + h1seq [Tc,1024,100]
    // + pre2 [Tc,1024,200] + small states. Tc=64 -> ~185 MB.
    int Tc = 64;
    auto need = [](int tc) -> size_t {
        return ((size_t)tc * 1024 * (400 + 100 + 200) +
                (size_t)1024 * 100 + (size_t)1024 * 50 * 2) * sizeof(float);
    };
    while (Tc > 1 && need(Tc) > ws_size) Tc >>= 1;

    float* pre1 = ws;
    float* h1s  = pre1 + (size_t)Tc * 1024 * 400;
    float* pre2 = h1s  + (size_t)Tc * 1024 * 100;
    float* c1   = pre2 + (size_t)Tc * 1024 * 200;
    float* c2   = c1 + 1024 * 100;
    float* h2st = c2 + 1024 * 50;

    const int nch = TT / Tc;
    for (int ch = 0; ch < nch; ch++) {
        int t0 = ch * Tc;
        gemm_pre<80, 81, 400, true ><<<dim3(7, Tc * 8), 256, 0, stream>>>(
            x, Wih1, bih1, bhh1, pre1, t0);
        rec1<<<dim3(256), dim3(832), 0, stream>>>(pre1, Whh1, h1s, c1, Tc, ch == 0 ? 1 : 0);
        gemm_pre<100, 101, 200, false><<<dim3(4, Tc * 8), 256, 0, stream>>>(
            h1s, Wih2, bih2, bhh2, pre2, 0);
        rec2<<<dim3(256), dim3(448), 0, stream>>>(pre2, Whh2, c2, h2st, out, Tc, ch == 0 ? 1 : 0);
    }
}

// Round 7
// 9172.832 us; speedup vs baseline: 1.0021x; 1.0007x over previous
//
#include <hip/hip_runtime.h>

#define BT 1024   // batch
#define TT 512    // total timesteps

__device__ __forceinline__ float sig_(float x) { return 1.f / (1.f + __expf(-x)); }
__device__ __forceinline__ float th_(float x)  { return 1.f - 2.f / (1.f + __expf(2.f * x)); }

// ---------------------------------------------------------------------------
// CONTROL ROUND: byte-identical resubmission of the Round-2 source (last
// version that executed end-to-end on this pipeline: passed, 9179 us).
// Purpose: split H-infra (broker outage since R3) from H-source (new rec-v2
// constructs hanging compile/launch). See round journal for the decision tree.
// ---------------------------------------------------------------------------

// ---------------------------------------------------------------------------
// pre[R][n] = sum_k Arow(R)[k] * W[n][k] + bih[n] + bhh[n]
// Row R = tl*1024 + b  (t-major within chunk, batch inner) so the recurrent
// kernel reads contiguous [b][n] slices per timestep.
// XMODE=true : A = x [B][T][K], row src = x + (b*TT + t0+tl)*K
// XMODE=false: A = h1seq, contiguous rows of length K.
// ---------------------------------------------------------------------------
template <int K, int KPAD, int N, bool XMODE>
__global__ __launch_bounds__(256) void gemm_pre(
    const float* __restrict__ A, const float* __restrict__ W,
    const float* __restrict__ bih, const float* __restrict__ bhh,
    float* __restrict__ out, int t0)
{
    __shared__ float As[128][KPAD];              // KPAD = K+1: 8-row lane stride -> <=2-way banks
    __shared__ __align__(16) float Bs[K][64];
    const int tid = threadIdx.x;
    const int n0 = blockIdx.x * 64;
    const int Rbase = blockIdx.y * 128;
    const int NQ = K / 4;

    // A tile: 128 rows x K, float4 per row-chunk, coalesced within rows
    for (int ii = tid; ii < 128 * NQ; ii += 256) {
        int r = ii / NQ, q = ii % NQ;
        const float* src;
        if (XMODE) {
            int b  = (blockIdx.y & 7) * 128 + r;   // 1024/128 = 8 blocks per tl
            int tl = blockIdx.y >> 3;
            src = A + ((size_t)b * TT + (t0 + tl)) * K;
        } else {
            src = A + (size_t)(Rbase + r) * K;
        }
        float4 v = *(const float4*)(src + q * 4);
        As[r][q * 4 + 0] = v.x; As[r][q * 4 + 1] = v.y;
        As[r][q * 4 + 2] = v.z; As[r][q * 4 + 3] = v.w;
    }
    // B tile transposed: Bs[k][n] = W[n0+n][k]; lane-gather from L2-hot W
    for (int ii = tid; ii < 64 * NQ; ii += 256) {
        int n = ii & 63, kq = ii >> 6;
        float4 v = make_float4(0.f, 0.f, 0.f, 0.f);
        if (n0 + n < N) v = *(const float4*)(W + (size_t)(n0 + n) * K + kq * 4);
        Bs[kq * 4 + 0][n] = v.x; Bs[kq * 4 + 1][n] = v.y;
        Bs[kq * 4 + 2][n] = v.z; Bs[kq * 4 + 3][n] = v.w;
    }
    __syncthreads();

    const int tx = tid & 15, ty = tid >> 4;      // 16x16 threads, 8x4 micro-tile
    float acc[8][4];
#pragma unroll
    for (int i = 0; i < 8; i++)
#pragma unroll
        for (int jj = 0; jj < 4; jj++) acc[i][jj] = 0.f;

#pragma unroll 4
    for (int k = 0; k < K; k++) {
        float4 bv = *(const float4*)&Bs[k][tx * 4];
#pragma unroll
        for (int i = 0; i < 8; i++) {
            float a = As[ty * 8 + i][k];
            acc[i][0] += a * bv.x; acc[i][1] += a * bv.y;
            acc[i][2] += a * bv.z; acc[i][3] += a * bv.w;
        }
    }
    int n = n0 + tx * 4;
    if (n < N) {
        float4 bias;
        bias.x = bih[n] + bhh[n];     bias.y = bih[n + 1] + bhh[n + 1];
        bias.z = bih[n + 2] + bhh[n + 2]; bias.w = bih[n + 3] + bhh[n + 3];
#pragma unroll
        for (int i = 0; i < 8; i++) {
            size_t R = (size_t)Rbase + ty * 8 + i;
            float4 o;
            o.x = acc[i][0] + bias.x; o.y = acc[i][1] + bias.y;
            o.z = acc[i][2] + bias.z; o.w = acc[i][3] + bias.w;
            *(float4*)(out + R * N + n) = o;
        }
    }
}

// ---------------------------------------------------------------------------
// rec1: layer-1 recurrence. 256 WGs x 832 thr (13 waves), 4 batch elems/WG.
// KNOWN-SPILLING (VGPR budget 64 -> w[52] to scratch); kept byte-identical
// to Round 2 as the infra control.
// ---------------------------------------------------------------------------
__global__ __launch_bounds__(832, 4) void rec1(
    const float* __restrict__ pre,   // [Tc][1024][400]
    const float* __restrict__ Whh,   // [400][100]
    float* __restrict__ hseq,        // [Tc][1024][100]
    float* __restrict__ cst,         // [1024][100]
    int Tc, int first)
{
    __shared__ __align__(16) float hs[4][104];
    __shared__ float pres[2][1600];
    __shared__ float gbuf[1600];
    const int tid = threadIdx.x;
    const int b0 = blockIdx.x * 4;
    const bool act = tid < 800;
    const int j  = tid >> 3;
    const int g  = (tid >> 1) & 3;
    const int kh = tid & 1;

    float w[52];
    if (act) {
        const int row = g * 100 + j;
#pragma unroll
        for (int kk = 0; kk < 52; kk++) {
            int k = kh * 52 + kk;
            w[kk] = (k < 100) ? Whh[row * 100 + k] : 0.f;
        }
    }
    const bool upd = tid < 400;
    const int ub = tid / 100, uj = tid % 100;
    float c = 0.f;
    if (upd) {
        if (first) {
            hs[ub][uj] = 0.f;
        } else {
            hs[ub][uj] = hseq[((size_t)(Tc - 1) * BT + b0 + ub) * 100 + uj];  // prev chunk's last h
            c = cst[(size_t)(b0 + ub) * 100 + uj];
        }
    }
    if (tid < 16) hs[tid >> 2][100 + (tid & 3)] = 0.f;  // zero pads
    for (int i = tid; i < 1600; i += 832)
        pres[0][i] = pre[(size_t)(b0 + i / 400) * 400 + (i % 400)];   // stage t=0
    const size_t pfA = (size_t)(b0 + tid / 400) * 400 + (tid % 400);
    const size_t pfB = (size_t)(b0 + (tid + 800) / 400) * 400 + ((tid + 800) % 400);
    __syncthreads();

    int cur = 0;
    for (int t = 0; t < Tc; t++) {
        // prefetch t+1 pre slice into registers (hidden under the k-loop)
        int tn = (t + 1 < Tc) ? (t + 1) : t;
        const float* pn = pre + (size_t)tn * BT * 400;
        float pf0 = pn[pfA];
        float pf1 = (tid < 800) ? pn[pfB] : 0.f;

        float a0 = 0.f, a1 = 0.f, a2 = 0.f, a3 = 0.f;
        if (act) {
            const float4* h0 = (const float4*)&hs[0][kh * 52];
            const float4* h1 = (const float4*)&hs[1][kh * 52];
            const float4* h2 = (const float4*)&hs[2][kh * 52];
            const float4* h3 = (const float4*)&hs[3][kh * 52];
#pragma unroll
            for (int q = 0; q < 13; q++) {
                float4 v0 = h0[q], v1 = h1[q], v2 = h2[q], v3 = h3[q];
                a0 += w[q*4+0]*v0.x + w[q*4+1]*v0.y + w[q*4+2]*v0.z + w[q*4+3]*v0.w;
                a1 += w[q*4+0]*v1.x + w[q*4+1]*v1.y + w[q*4+2]*v1.z + w[q*4+3]*v1.w;
                a2 += w[q*4+0]*v2.x + w[q*4+1]*v2.y + w[q*4+2]*v2.z + w[q*4+3]*v2.w;
                a3 += w[q*4+0]*v3.x + w[q*4+1]*v3.y + w[q*4+2]*v3.z + w[q*4+3]*v3.w;
            }
        }
        a0 += __shfl_xor(a0, 1); a1 += __shfl_xor(a1, 1);
        a2 += __shfl_xor(a2, 1); a3 += __shfl_xor(a3, 1);
        if (act && kh == 0) {
            int idx = g * 100 + j;
            gbuf[idx] = a0; gbuf[400 + idx] = a1; gbuf[800 + idx] = a2; gbuf[1200 + idx] = a3;
        }
        __syncthreads();
        if (upd) {
            const float* gb = gbuf + ub * 400;
            const float* pb = pres[cur] + ub * 400;
            float xi = gb[uj]       + pb[uj];
            float xf = gb[100 + uj] + pb[100 + uj];
            float xg = gb[200 + uj] + pb[200 + uj];
            float xo = gb[300 + uj] + pb[300 + uj];
            float ii = sig_(xi), ff = sig_(xf), gg = th_(xg), oo = sig_(xo);
            c = ff * c + ii * gg;
            float h = oo * th_(c);
            hs[ub][uj] = h;
            hseq[((size_t)t * BT + b0 + ub) * 100 + uj] = h;   // coalesced 400B segments
        }
        pres[cur ^ 1][tid] = pf0;
        if (tid < 800) pres[cur ^ 1][tid + 800] = pf1;
        __syncthreads();
        cur ^= 1;
    }
    if (upd) cst[(size_t)(b0 + ub) * 100 + uj] = c;
}

// ---------------------------------------------------------------------------
// rec2: layer-2 recurrence (H=50). Same structure at half size; no hidden
// sequence output — only state carry and the final [1024,50] -> d_out.
// ---------------------------------------------------------------------------
__global__ __launch_bounds__(448, 4) void rec2(
    const float* __restrict__ pre2,  // [Tc][1024][200]
    const float* __restrict__ Whh,   // [200][50]
    float* __restrict__ cst, float* __restrict__ hst,  // [1024][50]
    float* __restrict__ out,         // [1024][50]
    int Tc, int first)
{
    __shared__ __align__(16) float hs[4][56];
    __shared__ float pres[2][800];
    __shared__ float gbuf[800];
    const int tid = threadIdx.x;
    const int b0 = blockIdx.x * 4;
    const bool act = tid < 400;
    const int j  = tid >> 3;
    const int g  = (tid >> 1) & 3;
    const int kh = tid & 1;

    float w[28];
    if (act) {
        const int row = g * 50 + j;
#pragma unroll
        for (int kk = 0; kk < 28; kk++) {
            int k = kh * 28 + kk;
            w[kk] = (k < 50) ? Whh[row * 50 + k] : 0.f;
        }
    }
    const bool upd = tid < 200;
    const int ub = tid / 50, uj = tid % 50;
    float c = 0.f, h = 0.f;
    if (upd) {
        if (!first) {
            h = hst[(size_t)(b0 + ub) * 50 + uj];
            c = cst[(size_t)(b0 + ub) * 50 + uj];
        }
        hs[ub][uj] = h;
    }
    if (tid < 24) hs[tid / 6][50 + tid % 6] = 0.f;
    for (int i = tid; i < 800; i += 448)
        pres[0][i] = pre2[(size_t)(b0 + i / 200) * 200 + (i % 200)];
    const size_t pfA = (size_t)(b0 + tid / 200) * 200 + (tid % 200);
    const size_t pfB = (size_t)(b0 + (tid + 448) / 200) * 200 + ((tid + 448) % 200);
    __syncthreads();

    int cur = 0;
    for (int t = 0; t < Tc; t++) {
        int tn = (t + 1 < Tc) ? (t + 1) : t;
        const float* pn = pre2 + (size_t)tn * BT * 200;
        float pf0 = pn[pfA];
        float pf1 = (tid < 352) ? pn[pfB] : 0.f;

        float a0 = 0.f, a1 = 0.f, a2 = 0.f, a3 = 0.f;
        if (act) {
            const float4* h0 = (const float4*)&hs[0][kh * 28];
            const float4* h1 = (const float4*)&hs[1][kh * 28];
            const float4* h2 = (const float4*)&hs[2][kh * 28];
            const float4* h3 = (const float4*)&hs[3][kh * 28];
#pragma unroll
            for (int q = 0; q < 7; q++) {
                float4 v0 = h0[q], v1 = h1[q], v2 = h2[q], v3 = h3[q];
                a0 += w[q*4+0]*v0.x + w[q*4+1]*v0.y + w[q*4+2]*v0.z + w[q*4+3]*v0.w;
                a1 += w[q*4+0]*v1.x + w[q*4+1]*v1.y + w[q*4+2]*v1.z + w[q*4+3]*v1.w;
                a2 += w[q*4+0]*v2.x + w[q*4+1]*v2.y + w[q*4+2]*v2.z + w[q*4+3]*v2.w;
                a3 += w[q*4+0]*v3.x + w[q*4+1]*v3.y + w[q*4+2]*v3.z + w[q*4+3]*v3.w;
            }
        }
        a0 += __shfl_xor(a0, 1); a1 += __shfl_xor(a1, 1);
        a2 += __shfl_xor(a2, 1); a3 += __shfl_xor(a3, 1);
        if (act && kh == 0) {
            int idx = g * 50 + j;
            gbuf[idx] = a0; gbuf[200 + idx] = a1; gbuf[400 + idx] = a2; gbuf[600 + idx] = a3;
        }
        __syncthreads();
        if (upd) {
            const float* gb = gbuf + ub * 200;
            const float* pb = pres[cur] + ub * 200;
            float xi = gb[uj]       + pb[uj];
            float xf = gb[50 + uj]  + pb[50 + uj];
            float xg = gb[100 + uj] + pb[100 + uj];
            float xo = gb[150 + uj] + pb[150 + uj];
            float ii = sig_(xi), ff = sig_(xf), gg = th_(xg), oo = sig_(xo);
            c = ff * c + ii * gg;
            h = oo * th_(c);
            hs[ub][uj] = h;
        }
        pres[cur ^ 1][tid] = pf0;
        if (tid < 352) pres[cur ^ 1][tid + 448] = pf1;
        __syncthreads();
        cur ^= 1;
    }
    if (upd) {
        cst[(size_t)(b0 + ub) * 50 + uj] = c;
        hst[(size_t)(b0 + ub) * 50 + uj] = h;
        out[(size_t)(b0 + ub) * 50 + uj] = h;
    }
}

// ---------------------------------------------------------------------------
extern "C" void kernel_launch(void* const* d_in, const int* in_sizes, int n_in,
                              void* d_out, int out_size, void* d_ws, size_t ws_size,
                              hipStream_t stream)
{
    const float* x    = (const float*)d_in[0];
    const float* Wih1 = (const float*)d_in[1];
    const float* Whh1 = (const float*)d_in[2];
    const float* bih1 = (const float*)d_in[3];
    const float* bhh1 = (const float*)d_in[4];
    const float* Wih2 = (const float*)d_in[5];
    const float* Whh2 = (const float*)d_in[6];
    const float* bih2 = (const float*)d_in[7];
    const float* bhh2 = (const float*)d_in[8];
    float* out = (float*)d_out;
    float* ws  = (float*)d_ws;

    // Chunk T so scratch fits: per chunk pre1 [Tc,1024,400] + h1seq [Tc,1024,100]
    // + pre2 [Tc,1024,200] + small states. Tc=64 -> ~185 MB.
    int Tc = 64;
    auto need = [](int tc) -> size_t {
        return ((size_t)tc * 1024 * (400 + 100 + 200) +
                (size_t)1024 * 100 + (size_t)1024 * 50 * 2) * sizeof(float);
    };
    while (Tc > 1 && need(Tc) > ws_size) Tc >>= 1;

    float* pre1 = ws;
    float* h1s  = pre1 + (size_t)Tc * 1024 * 400;
    float* pre2 = h1s  + (size_t)Tc * 1024 * 100;
    float* c1   = pre2 + (size_t)Tc * 1024 * 200;
    float* c2   = c1 + 1024 * 100;
    float* h2st = c2 + 1024 * 50;

    const int nch = TT / Tc;
    for (int ch = 0; ch < nch; ch++) {
        int t0 = ch * Tc;
        gemm_pre<80, 81, 400, true ><<<dim3(7, Tc * 8), 256, 0, stream>>>(
            x, Wih1, bih1, bhh1, pre1, t0);
        rec1<<<dim3(256), dim3(832), 0, stream>>>(pre1, Whh1, h1s, c1, Tc, ch == 0 ? 1 : 0);
        gemm_pre<100, 101, 200, false><<<dim3(4, Tc * 8), 256, 0, stream>>>(
            h1s, Wih2, bih2, bhh2, pre2, 0);
        rec2<<<dim3(256), dim3(448), 0, stream>>>(pre2, Whh2, c2, h2st, out, Tc, ch == 0 ? 1 : 0);
    }
}

// Round 8
// 5175.496 us; speedup vs baseline: 1.7762x; 1.7724x over previous
//
#include <hip/hip_runtime.h>

#define BT 1024   // batch
#define TT 512    // total timesteps

__device__ __forceinline__ float sig_(float x) { return 1.f / (1.f + __expf(-x)); }
__device__ __forceinline__ float th_(float x)  { return 1.f - 2.f / (1.f + __expf(2.f * x)); }

// ---------------------------------------------------------------------------
// pre[R][n] = sum_k Arow(R)[k] * W[n][k] + bih[n] + bhh[n]
// Row R = tl*1024 + b  (t-major within chunk, batch inner) so the recurrent
// kernel reads contiguous [b][n] slices per timestep.
// XMODE=true : A = x [B][T][K], row src = x + (b*TT + t0+tl)*K
// XMODE=false: A = h1seq, contiguous rows of length K.
// ---------------------------------------------------------------------------
template <int K, int KPAD, int N, bool XMODE>
__global__ __launch_bounds__(256) void gemm_pre(
    const float* __restrict__ A, const float* __restrict__ W,
    const float* __restrict__ bih, const float* __restrict__ bhh,
    float* __restrict__ out, int t0)
{
    __shared__ float As[128][KPAD];              // KPAD = K+1: 8-row lane stride -> <=2-way banks
    __shared__ __align__(16) float Bs[K][64];
    const int tid = threadIdx.x;
    const int n0 = blockIdx.x * 64;
    const int Rbase = blockIdx.y * 128;
    const int NQ = K / 4;

    // A tile: 128 rows x K, float4 per row-chunk, coalesced within rows
    for (int ii = tid; ii < 128 * NQ; ii += 256) {
        int r = ii / NQ, q = ii % NQ;
        const float* src;
        if (XMODE) {
            int b  = (blockIdx.y & 7) * 128 + r;   // 1024/128 = 8 blocks per tl
            int tl = blockIdx.y >> 3;
            src = A + ((size_t)b * TT + (t0 + tl)) * K;
        } else {
            src = A + (size_t)(Rbase + r) * K;
        }
        float4 v = *(const float4*)(src + q * 4);
        As[r][q * 4 + 0] = v.x; As[r][q * 4 + 1] = v.y;
        As[r][q * 4 + 2] = v.z; As[r][q * 4 + 3] = v.w;
    }
    // B tile transposed: Bs[k][n] = W[n0+n][k]; lane-gather from L2-hot W
    for (int ii = tid; ii < 64 * NQ; ii += 256) {
        int n = ii & 63, kq = ii >> 6;
        float4 v = make_float4(0.f, 0.f, 0.f, 0.f);
        if (n0 + n < N) v = *(const float4*)(W + (size_t)(n0 + n) * K + kq * 4);
        Bs[kq * 4 + 0][n] = v.x; Bs[kq * 4 + 1][n] = v.y;
        Bs[kq * 4 + 2][n] = v.z; Bs[kq * 4 + 3][n] = v.w;
    }
    __syncthreads();

    const int tx = tid & 15, ty = tid >> 4;      // 16x16 threads, 8x4 micro-tile
    float acc[8][4];
#pragma unroll
    for (int i = 0; i < 8; i++)
#pragma unroll
        for (int jj = 0; jj < 4; jj++) acc[i][jj] = 0.f;

#pragma unroll 4
    for (int k = 0; k < K; k++) {
        float4 bv = *(const float4*)&Bs[k][tx * 4];
#pragma unroll
        for (int i = 0; i < 8; i++) {
            float a = As[ty * 8 + i][k];
            acc[i][0] += a * bv.x; acc[i][1] += a * bv.y;
            acc[i][2] += a * bv.z; acc[i][3] += a * bv.w;
        }
    }
    int n = n0 + tx * 4;
    if (n < N) {
        float4 bias;
        bias.x = bih[n] + bhh[n];     bias.y = bih[n + 1] + bhh[n + 1];
        bias.z = bih[n + 2] + bhh[n + 2]; bias.w = bih[n + 3] + bhh[n + 3];
#pragma unroll
        for (int i = 0; i < 8; i++) {
            size_t R = (size_t)Rbase + ty * 8 + i;
            float4 o;
            o.x = acc[i][0] + bias.x; o.y = acc[i][1] + bias.y;
            o.z = acc[i][2] + bias.z; o.w = acc[i][3] + bias.w;
            *(float4*)(out + R * N + n) = o;
        }
    }
}

// ---------------------------------------------------------------------------
// rec1 v2: layer-1 recurrence, 256 WGs x 256 thr (4 waves), 4 batch elems/WG.
// Each compute thread (tid<200: j=tid%100, gp=tid/100) owns TWO full Whh rows
// (gp*200+j and gp*200+100+j; full k=100) in VGPRs: 50 float4 = 200 VGPRs.
// Full-k ownership -> complete dot products in-thread: no shfl, no k-reduce,
// and h is read once per (batch,q) as broadcast float4 (conflict-free).
//
// REGISTER-BUDGET LESSON (R1-R7): 13-wave WGs force the RA into a <=64-VGPR
// budget -> w[] spills -> 2.7 GB/dispatch HBM fetch (R1/R2/R7 counter-proven).
// All four container failures (R3-R6) had min-waves=1 configs (waves_per_eu
// (1,4) or __launch_bounds__(256,1)); every source that ran used min>=4.
// So: __launch_bounds__(256, 2) -> 8 waves = exactly 2/EU with 2 resident
// WGs -> deterministic 256-VGPR budget, fits ~240 live regs, avoids the
// suspect min=1 path. Do not change to (X,1) or waves_per_eu.
// ---------------------------------------------------------------------------
__global__ __launch_bounds__(256, 2) void rec1(
    const float* __restrict__ pre,   // [Tc][1024][400]
    const float* __restrict__ Whh,   // [400][100]
    float* __restrict__ hseq,        // [Tc][1024][100]
    float* __restrict__ cst,         // [1024][100]
    int Tc, int first)
{
    __shared__ __align__(16) float hs[4][100];     // 400B row stride, 16B-aligned
    __shared__ __align__(16) float pres[2][1600];
    __shared__ float gbuf[1600];                   // [gate][b][j]
    const int tid = threadIdx.x;
    const int b0 = blockIdx.x * 4;

    const bool comp = tid < 200;
    const int j  = tid % 100;
    const int gp = tid / 100;                      // 0: gates i,f ; 1: gates g,o

    float4 w0[25], w1[25];                         // two rows, 200 VGPRs
    if (comp) {
        const float4* W0 = (const float4*)(Whh + (size_t)(gp * 200 + j) * 100);
        const float4* W1 = (const float4*)(Whh + (size_t)(gp * 200 + 100 + j) * 100);
#pragma unroll
        for (int q = 0; q < 25; q++) { w0[q] = W0[q]; w1[q] = W1[q]; }
    }

    // update units: u0 = tid (0..255), u1 = tid+256 (256..399, tid<144)
    const int u0b = tid / 100, u0j = tid % 100;
    const bool hasu1 = (tid + 256) < 400;
    const int u1b = (tid + 256) / 100, u1j = (tid + 256) % 100;
    float c0 = 0.f, c1 = 0.f;
    if (first) {
        hs[u0b][u0j] = 0.f;
        if (hasu1) hs[u1b][u1j] = 0.f;
    } else {
        hs[u0b][u0j] = hseq[((size_t)(Tc - 1) * BT + b0 + u0b) * 100 + u0j];
        c0 = cst[(size_t)(b0 + u0b) * 100 + u0j];
        if (hasu1) {
            hs[u1b][u1j] = hseq[((size_t)(Tc - 1) * BT + b0 + u1b) * 100 + u1j];
            c1 = cst[(size_t)(b0 + u1b) * 100 + u1j];
        }
    }
    {   // stage pres[0]: 1600 contiguous floats = 400 float4
        const float4* p4 = (const float4*)(pre + (size_t)b0 * 400);
        float4* d = (float4*)pres[0];
        d[tid] = p4[tid];
        if (tid < 144) d[tid + 256] = p4[tid + 256];
    }
    __syncthreads();

    int cur = 0;
    for (int t = 0; t < Tc; t++) {
        // prefetch t+1 pre slice into registers (hidden under the k-loop)
        int tn = (t + 1 < Tc) ? (t + 1) : t;
        const float4* p4 = (const float4*)(pre + (size_t)tn * BT * 400 + (size_t)b0 * 400);
        float4 pf0 = p4[tid];
        float4 pf1 = (tid < 144) ? p4[tid + 256] : make_float4(0.f, 0.f, 0.f, 0.f);

        float accA[4] = {0.f, 0.f, 0.f, 0.f};
        float accB[4] = {0.f, 0.f, 0.f, 0.f};
        if (comp) {
            const float4* h0 = (const float4*)hs[0];
            const float4* h1 = (const float4*)hs[1];
            const float4* h2 = (const float4*)hs[2];
            const float4* h3 = (const float4*)hs[3];
#pragma unroll
            for (int q = 0; q < 25; q++) {
                float4 wa = w0[q], wb = w1[q];
                float4 v;
                v = h0[q];
                accA[0] += wa.x*v.x + wa.y*v.y + wa.z*v.z + wa.w*v.w;
                accB[0] += wb.x*v.x + wb.y*v.y + wb.z*v.z + wb.w*v.w;
                v = h1[q];
                accA[1] += wa.x*v.x + wa.y*v.y + wa.z*v.z + wa.w*v.w;
                accB[1] += wb.x*v.x + wb.y*v.y + wb.z*v.z + wb.w*v.w;
                v = h2[q];
                accA[2] += wa.x*v.x + wa.y*v.y + wa.z*v.z + wa.w*v.w;
                accB[2] += wb.x*v.x + wb.y*v.y + wb.z*v.z + wb.w*v.w;
                v = h3[q];
                accA[3] += wa.x*v.x + wa.y*v.y + wa.z*v.z + wa.w*v.w;
                accB[3] += wb.x*v.x + wb.y*v.y + wb.z*v.z + wb.w*v.w;
            }
            int base = (gp * 2) * 400 + j;
#pragma unroll
            for (int bb = 0; bb < 4; bb++) gbuf[base + bb * 100] = accA[bb];
            base += 400;
#pragma unroll
            for (int bb = 0; bb < 4; bb++) gbuf[base + bb * 100] = accB[bb];
        }
        __syncthreads();   // gbuf ready; everyone done reading hs & pres[cur]

        {   // update (all 256 threads have u0; 144 have u1)
            const float* pb = pres[cur];
            {
                float xi = gbuf[u0b * 100 + u0j]        + pb[u0b * 400 + u0j];
                float xf = gbuf[400 + u0b * 100 + u0j]  + pb[u0b * 400 + 100 + u0j];
                float xg = gbuf[800 + u0b * 100 + u0j]  + pb[u0b * 400 + 200 + u0j];
                float xo = gbuf[1200 + u0b * 100 + u0j] + pb[u0b * 400 + 300 + u0j];
                float ii = sig_(xi), ff = sig_(xf), gg = th_(xg), oo = sig_(xo);
                c0 = ff * c0 + ii * gg;
                float h = oo * th_(c0);
                hs[u0b][u0j] = h;
                hseq[((size_t)t * BT + b0 + u0b) * 100 + u0j] = h;
            }
            if (hasu1) {
                float xi = gbuf[u1b * 100 + u1j]        + pb[u1b * 400 + u1j];
                float xf = gbuf[400 + u1b * 100 + u1j]  + pb[u1b * 400 + 100 + u1j];
                float xg = gbuf[800 + u1b * 100 + u1j]  + pb[u1b * 400 + 200 + u1j];
                float xo = gbuf[1200 + u1b * 100 + u1j] + pb[u1b * 400 + 300 + u1j];
                float ii = sig_(xi), ff = sig_(xf), gg = th_(xg), oo = sig_(xo);
                c1 = ff * c1 + ii * gg;
                float h = oo * th_(c1);
                hs[u1b][u1j] = h;
                hseq[((size_t)t * BT + b0 + u1b) * 100 + u1j] = h;
            }
        }
        {   // commit prefetched pre into the next buffer
            float4* d = (float4*)pres[cur ^ 1];
            d[tid] = pf0;
            if (tid < 144) d[tid + 256] = pf1;
        }
        __syncthreads();   // hs & pres[nxt] ready
        cur ^= 1;
    }
    cst[(size_t)(b0 + u0b) * 100 + u0j] = c0;
    if (hasu1) cst[(size_t)(b0 + u1b) * 100 + u1j] = c1;
}

// ---------------------------------------------------------------------------
// rec2 v2: layer-2 (H=50), same structure. Compute threads tid<100 own two
// rows (k padded 50->52 with zeros; Whh2 rows are 200B so float4 loads would
// be misaligned for odd rows -> scalar one-time load). ~110 VGPRs used.
// Same (256,2) rationale as rec1.
// ---------------------------------------------------------------------------
__global__ __launch_bounds__(256, 2) void rec2(
    const float* __restrict__ pre2,  // [Tc][1024][200]
    const float* __restrict__ Whh,   // [200][50]
    float* __restrict__ cst, float* __restrict__ hst,  // [1024][50]
    float* __restrict__ out,         // [1024][50]
    int Tc, int first)
{
    __shared__ __align__(16) float hs[4][52];      // 208B row stride, 16B-aligned
    __shared__ __align__(16) float pres[2][800];
    __shared__ float gbuf[800];                    // [gate][b][j]
    const int tid = threadIdx.x;
    const int b0 = blockIdx.x * 4;
    const bool comp = tid < 100;
    const int j  = tid % 50;
    const int gp = tid / 50;                       // 0: gates i,f ; 1: gates g,o

    float4 w0[13], w1[13];
    if (comp) {
        const float* W0 = Whh + (size_t)(gp * 100 + j) * 50;
        const float* W1 = Whh + (size_t)(gp * 100 + 50 + j) * 50;
#pragma unroll
        for (int q = 0; q < 13; q++) {
            int k = q * 4;
            w0[q].x = (k + 0 < 50) ? W0[k + 0] : 0.f;
            w0[q].y = (k + 1 < 50) ? W0[k + 1] : 0.f;
            w0[q].z = (k + 2 < 50) ? W0[k + 2] : 0.f;
            w0[q].w = (k + 3 < 50) ? W0[k + 3] : 0.f;
            w1[q].x = (k + 0 < 50) ? W1[k + 0] : 0.f;
            w1[q].y = (k + 1 < 50) ? W1[k + 1] : 0.f;
            w1[q].z = (k + 2 < 50) ? W1[k + 2] : 0.f;
            w1[q].w = (k + 3 < 50) ? W1[k + 3] : 0.f;
        }
    }

    const bool upd = tid < 200;
    const int ub = tid / 50, uj = tid % 50;
    float c = 0.f, hlast = 0.f;
    if (upd) {
        float h = 0.f;
        if (!first) {
            h = hst[(size_t)(b0 + ub) * 50 + uj];
            c = cst[(size_t)(b0 + ub) * 50 + uj];
        }
        hs[ub][uj] = h;
        hlast = h;
    }
    if (tid >= 200 && tid < 208) {                 // zero the 2 pad cols x 4 rows
        int p = tid - 200;
        hs[p >> 1][50 + (p & 1)] = 0.f;
    }
    {   // stage pres[0]: 800 contiguous floats = 200 float4
        const float4* p4 = (const float4*)(pre2 + (size_t)b0 * 200);
        if (tid < 200) ((float4*)pres[0])[tid] = p4[tid];
    }
    __syncthreads();

    int cur = 0;
    for (int t = 0; t < Tc; t++) {
        int tn = (t + 1 < Tc) ? (t + 1) : t;
        const float4* p4 = (const float4*)(pre2 + (size_t)tn * BT * 200 + (size_t)b0 * 200);
        float4 pf0 = (tid < 200) ? p4[tid] : make_float4(0.f, 0.f, 0.f, 0.f);

        float accA[4] = {0.f, 0.f, 0.f, 0.f};
        float accB[4] = {0.f, 0.f, 0.f, 0.f};
        if (comp) {
            const float4* h0 = (const float4*)hs[0];
            const float4* h1 = (const float4*)hs[1];
            const float4* h2 = (const float4*)hs[2];
            const float4* h3 = (const float4*)hs[3];
#pragma unroll
            for (int q = 0; q < 13; q++) {
                float4 wa = w0[q], wb = w1[q];
                float4 v;
                v = h0[q];
                accA[0] += wa.x*v.x + wa.y*v.y + wa.z*v.z + wa.w*v.w;
                accB[0] += wb.x*v.x + wb.y*v.y + wb.z*v.z + wb.w*v.w;
                v = h1[q];
                accA[1] += wa.x*v.x + wa.y*v.y + wa.z*v.z + wa.w*v.w;
                accB[1] += wb.x*v.x + wb.y*v.y + wb.z*v.z + wb.w*v.w;
                v = h2[q];
                accA[2] += wa.x*v.x + wa.y*v.y + wa.z*v.z + wa.w*v.w;
                accB[2] += wb.x*v.x + wb.y*v.y + wb.z*v.z + wb.w*v.w;
                v = h3[q];
                accA[3] += wa.x*v.x + wa.y*v.y + wa.z*v.z + wa.w*v.w;
                accB[3] += wb.x*v.x + wb.y*v.y + wb.z*v.z + wb.w*v.w;
            }
            int base = (gp * 2) * 200 + j;
#pragma unroll
            for (int bb = 0; bb < 4; bb++) gbuf[base + bb * 50] = accA[bb];
            base += 200;
#pragma unroll
            for (int bb = 0; bb < 4; bb++) gbuf[base + bb * 50] = accB[bb];
        }
        __syncthreads();

        if (upd) {
            const float* pb = pres[cur];
            float xi = gbuf[ub * 50 + uj]       + pb[ub * 200 + uj];
            float xf = gbuf[200 + ub * 50 + uj] + pb[ub * 200 + 50 + uj];
            float xg = gbuf[400 + ub * 50 + uj] + pb[ub * 200 + 100 + uj];
            float xo = gbuf[600 + ub * 50 + uj] + pb[ub * 200 + 150 + uj];
            float ii = sig_(xi), ff = sig_(xf), gg = th_(xg), oo = sig_(xo);
            c = ff * c + ii * gg;
            float h = oo * th_(c);
            hs[ub][uj] = h;
            hlast = h;
        }
        if (tid < 200) ((float4*)pres[cur ^ 1])[tid] = pf0;
        __syncthreads();
        cur ^= 1;
    }
    if (upd) {
        cst[(size_t)(b0 + ub) * 50 + uj] = c;
        hst[(size_t)(b0 + ub) * 50 + uj] = hlast;
        out[(size_t)(b0 + ub) * 50 + uj] = hlast;
    }
}

// ---------------------------------------------------------------------------
extern "C" void kernel_launch(void* const* d_in, const int* in_sizes, int n_in,
                              void* d_out, int out_size, void* d_ws, size_t ws_size,
                              hipStream_t stream)
{
    const float* x    = (const float*)d_in[0];
    const float* Wih1 = (const float*)d_in[1];
    const float* Whh1 = (const float*)d_in[2];
    const float* bih1 = (const float*)d_in[3];
    const float* bhh1 = (const float*)d_in[4];
    const float* Wih2 = (const float*)d_in[5];
    const float* Whh2 = (const float*)d_in[6];
    const float* bih2 = (const float*)d_in[7];
    const float* bhh2 = (const float*)d_in[8];
    float* out = (float*)d_out;
    float* ws  = (float*)d_ws;

    // Chunk T so scratch fits: per chunk pre1 [Tc,1024,400] + h1seq [Tc,1024,100]
    // + pre2 [Tc,1024,200] + small states. Tc=64 -> ~185 MB.
    int Tc = 64;
    auto need = [](int tc) -> size_t {
        return ((size_t)tc * 1024 * (400 + 100 + 200) +
                (size_t)1024 * 100 + (size_t)1024 * 50 * 2) * sizeof(float);
    };
    while (Tc > 1 && need(Tc) > ws_size) Tc >>= 1;

    float* pre1 = ws;
    float* h1s  = pre1 + (size_t)Tc * 1024 * 400;
    float* pre2 = h1s  + (size_t)Tc * 1024 * 100;
    float* c1   = pre2 + (size_t)Tc * 1024 * 200;
    float* c2   = c1 + 1024 * 100;
    float* h2st = c2 + 1024 * 50;

    const int nch = TT / Tc;
    for (int ch = 0; ch < nch; ch++) {
        int t0 = ch * Tc;
        gemm_pre<80, 81, 400, true ><<<dim3(7, Tc * 8), 256, 0, stream>>>(
            x, Wih1, bih1, bhh1, pre1, t0);
        rec1<<<dim3(256), dim3(256), 0, stream>>>(pre1, Whh1, h1s, c1, Tc, ch == 0 ? 1 : 0);
        gemm_pre<100, 101, 200, false><<<dim3(4, Tc * 8), 256, 0, stream>>>(
            h1s, Wih2, bih2, bhh2, pre2, 0);
        rec2<<<dim3(256), dim3(256), 0, stream>>>(pre2, Whh2, c2, h2st, out, Tc, ch == 0 ? 1 : 0);
    }
}